// Round 1
// baseline (455.879 us; speedup 1.0000x reference)
//
#include <hip/hip_runtime.h>
#include <hip/hip_bf16.h>

#define NB 8
#define SEQ 2048
#define DIM 512

typedef __attribute__((ext_vector_type(8))) short short8;
typedef __attribute__((ext_vector_type(4))) float f32x4;
typedef __attribute__((ext_vector_type(4))) unsigned short ushort4v;

#define MFMA(a, b, c) __builtin_amdgcn_mfma_f32_16x16x32_bf16((a), (b), (c), 0, 0, 0)

__device__ __forceinline__ unsigned short f2bf(float f) {
    unsigned int u = __float_as_uint(f);
    unsigned int r = (u + 0x7fffu + ((u >> 16) & 1u)) >> 16;
    return (unsigned short)r;
}
__device__ __forceinline__ float bf2f(unsigned short h) {
    return __uint_as_float(((unsigned int)h) << 16);
}

// ---------------- K0: split W into hi/lo bf16 and transpose to [n][k] -------
__global__ __launch_bounds__(256) void k0_split_w(
    const float* __restrict__ Wq, const float* __restrict__ Wk, const float* __restrict__ Wv,
    unsigned short* __restrict__ wth, unsigned short* __restrict__ wtl) {
    int idx = blockIdx.x * 256 + threadIdx.x;   // [0, 3*512*512)
    int p = idx >> 18;
    int rem = idx & 262143;
    int k = rem >> 9, n = rem & 511;
    const float* W = (p == 0) ? Wq : (p == 1) ? Wk : Wv;
    float w = W[rem];
    unsigned short h = f2bf(w);
    unsigned short l = f2bf(w - bf2f(h));
    wth[(p << 18) + (n << 9) + k] = h;
    wtl[(p << 18) + (n << 9) + k] = l;
}

// ---------------- K1: projection GEMM (split-bf16, 3 terms) -----------------
// C[16384,512] = X[16384,512] @ W[512,512] + b ; p=0->Q(h,l) p=1->K(h,l) p=2->V^T
__global__ __launch_bounds__(256) void k1_proj(
    const float* __restrict__ x,
    const unsigned short* __restrict__ wth, const unsigned short* __restrict__ wtl,
    const float* __restrict__ bq, const float* __restrict__ bk, const float* __restrict__ bv,
    unsigned short* __restrict__ qh, unsigned short* __restrict__ ql,
    unsigned short* __restrict__ kh, unsigned short* __restrict__ kl,
    unsigned short* __restrict__ vt) {
    __shared__ unsigned short ah[128 * 40];  // X hi tile [128 m][32 k], pad 40
    __shared__ unsigned short al[128 * 40];
    __shared__ unsigned short bh[128 * 40];  // Wt hi tile [128 n][32 k], pad 40
    __shared__ unsigned short bl[128 * 40];

    int tid = threadIdx.x;
    int m0 = blockIdx.x * 128, n0 = blockIdx.y * 128, p = blockIdx.z;
    const unsigned short* wh = wth + (p << 18);
    const unsigned short* wl = wtl + (p << 18);
    const float* bias = (p == 0) ? bq : (p == 1) ? bk : bv;
    int wid = tid >> 6, lane = tid & 63, r = lane & 15, g = lane >> 4;
    int mw = wid >> 1, nw = wid & 1;

    f32x4 acc[4][4];
    for (int m = 0; m < 4; ++m)
        for (int n = 0; n < 4; ++n) acc[m][n] = (f32x4)(0.0f);

    for (int kt = 0; kt < 16; ++kt) {
        int k0 = kt * 32;
        __syncthreads();
        // stage X tile, splitting fp32 -> hi/lo bf16
        for (int j = 0; j < 4; ++j) {
            int c = tid + 256 * j;            // 1024 float4 chunks: 128 rows x 8
            int row = c >> 3, slot = c & 7;
            float4 v = *(const float4*)(x + (size_t)(m0 + row) * 512 + k0 + slot * 4);
            ushort4v hv, lv;
            hv.x = f2bf(v.x); lv.x = f2bf(v.x - bf2f(hv.x));
            hv.y = f2bf(v.y); lv.y = f2bf(v.y - bf2f(hv.y));
            hv.z = f2bf(v.z); lv.z = f2bf(v.z - bf2f(hv.z));
            hv.w = f2bf(v.w); lv.w = f2bf(v.w - bf2f(hv.w));
            *(ushort4v*)(&ah[row * 40 + slot * 4]) = hv;
            *(ushort4v*)(&al[row * 40 + slot * 4]) = lv;
        }
        // stage Wt tiles (already split+transposed): [128 n][32 k]
        for (int j = 0; j < 2; ++j) {
            int c = tid + 256 * j;            // 512 chunks of 16B: 128 rows x 4
            int row = c >> 2, slot = c & 3;
            *(short8*)(&bh[row * 40 + slot * 8]) =
                *(const short8*)(wh + (size_t)(n0 + row) * 512 + k0 + slot * 8);
            *(short8*)(&bl[row * 40 + slot * 8]) =
                *(const short8*)(wl + (size_t)(n0 + row) * 512 + k0 + slot * 8);
        }
        __syncthreads();

        short8 afh[4], afl[4], bfh[4], bfl[4];
        for (int m = 0; m < 4; ++m) {
            int row = mw * 64 + m * 16 + r;
            afh[m] = *(const short8*)(&ah[row * 40 + g * 8]);
            afl[m] = *(const short8*)(&al[row * 40 + g * 8]);
        }
        for (int n = 0; n < 4; ++n) {
            int row = nw * 64 + n * 16 + r;
            bfh[n] = *(const short8*)(&bh[row * 40 + g * 8]);
            bfl[n] = *(const short8*)(&bl[row * 40 + g * 8]);
        }
        for (int m = 0; m < 4; ++m)
            for (int n = 0; n < 4; ++n) {
                acc[m][n] = MFMA(afh[m], bfh[n], acc[m][n]);
                acc[m][n] = MFMA(afh[m], bfl[n], acc[m][n]);
                acc[m][n] = MFMA(afl[m], bfh[n], acc[m][n]);
            }
    }

    // epilogue
    for (int n = 0; n < 4; ++n) {
        int col = n0 + nw * 64 + n * 16 + r;
        float bi = bias[col];
        for (int m = 0; m < 4; ++m) {
            int grow0 = m0 + mw * 64 + m * 16 + 4 * g;
            if (p < 2) {
                unsigned short* oh = (p == 0) ? qh : kh;
                unsigned short* ol = (p == 0) ? ql : kl;
                for (int reg = 0; reg < 4; ++reg) {
                    float val = acc[m][n][reg] + bi;
                    unsigned short h = f2bf(val);
                    oh[(size_t)(grow0 + reg) * 512 + col] = h;
                    ol[(size_t)(grow0 + reg) * 512 + col] = f2bf(val - bf2f(h));
                }
            } else {
                // V transposed: vt[b][d][s], bf16
                int b = grow0 >> 11, s0 = grow0 & 2047;
                ushort4v pv;
                pv.x = f2bf(acc[m][n][0] + bi);
                pv.y = f2bf(acc[m][n][1] + bi);
                pv.z = f2bf(acc[m][n][2] + bi);
                pv.w = f2bf(acc[m][n][3] + bi);
                *(ushort4v*)(&vt[(size_t)b * (512 * 2048) + (size_t)col * 2048 + s0]) = pv;
            }
        }
    }
}

// ---------------- K2: fused flash attention -------------------------------
// block: 64 q rows, 8 waves = (q-half) x (d-chunk of 128). KV tile = 32.
#define SMEM_K2 157696
__global__ __launch_bounds__(512, 2) void k2_attn(
    const unsigned short* __restrict__ qhp, const unsigned short* __restrict__ qlp,
    const unsigned short* __restrict__ khp, const unsigned short* __restrict__ klp,
    const unsigned short* __restrict__ vtp, float* __restrict__ out) {
    extern __shared__ char smem[];
    unsigned short* kh_s = (unsigned short*)smem;              // [32][520]
    unsigned short* kl_s = (unsigned short*)(smem + 33280);    // [32][520]
    unsigned short* vt_s = (unsigned short*)(smem + 66560);    // [512][40]
    float* par = (float*)(smem + 107520);                      // [2][4][32][44]
    unsigned short* p_s = (unsigned short*)(smem + 152576);    // [2][32][40]

    int tid = threadIdx.x;
    int wid = tid >> 6, lane = tid & 63, r = lane & 15, g = lane >> 4;
    int qhh = wid >> 2, dw = wid & 3;
    int nb = blockIdx.y, qt = blockIdx.x;
    int q0 = qt * 64;

    // Q fragments (hi/lo) for this wave's 32 q-rows x 128 d-chunk
    const size_t qrowbase = (size_t)(nb * SEQ + q0 + qhh * 32) * 512;
    short8 qfh[2][4], qfl[2][4];
    for (int m = 0; m < 2; ++m)
        for (int kt = 0; kt < 4; ++kt) {
            size_t idx = qrowbase + (size_t)(m * 16 + r) * 512 + dw * 128 + kt * 32 + g * 8;
            qfh[m][kt] = *(const short8*)(qhp + idx);
            qfl[m][kt] = *(const short8*)(qlp + idx);
        }

    f32x4 o[2][8];
    for (int m = 0; m < 2; ++m)
        for (int ns = 0; ns < 8; ++ns) o[m][ns] = (f32x4)(0.0f);
    float runm[2][4], runl[2][4];
    for (int m = 0; m < 2; ++m)
        for (int rg = 0; rg < 4; ++rg) { runm[m][rg] = -3.0e38f; runl[m][rg] = 0.0f; }

    for (int t = 0; t < 64; ++t) {
        const size_t kvrow = (size_t)(nb * SEQ + t * 32) * 512;
        __syncthreads();
        // stage K hi/lo: one wave-row = one 1KB K row; padded rows, conflict-free
        for (int j = 0; j < 4; ++j) {
            int c = tid + 512 * j;
            int row = c >> 6, slot = c & 63;
            *(short8*)(&kh_s[row * 520 + slot * 8]) =
                *(const short8*)(khp + kvrow + (size_t)row * 512 + slot * 8);
            *(short8*)(&kl_s[row * 520 + slot * 8]) =
                *(const short8*)(klp + kvrow + (size_t)row * 512 + slot * 8);
        }
        // stage V^T tile [512 d][32 kv]
        const size_t vbase = (size_t)nb * (512 * 2048) + (size_t)t * 32;
        for (int j = 0; j < 4; ++j) {
            int c = tid + 512 * j;
            int d = c >> 2, slot = c & 3;
            *(short8*)(&vt_s[d * 40 + slot * 8]) =
                *(const short8*)(vtp + vbase + (size_t)d * 2048 + slot * 8);
        }
        __syncthreads();

        // QK^T partial over this wave's 128-d chunk (3-term split)
        f32x4 sa[2][2];
        for (int m = 0; m < 2; ++m)
            for (int ns = 0; ns < 2; ++ns) sa[m][ns] = (f32x4)(0.0f);
        for (int kt = 0; kt < 4; ++kt) {
            for (int ns = 0; ns < 2; ++ns) {
                const short8 kfh = *(const short8*)(&kh_s[(r + 16 * ns) * 520 + dw * 128 + kt * 32 + g * 8]);
                const short8 kfl = *(const short8*)(&kl_s[(r + 16 * ns) * 520 + dw * 128 + kt * 32 + g * 8]);
                for (int m = 0; m < 2; ++m) {
                    sa[m][ns] = MFMA(qfh[m][kt], kfh, sa[m][ns]);
                    sa[m][ns] = MFMA(qfh[m][kt], kfl, sa[m][ns]);
                    sa[m][ns] = MFMA(qfl[m][kt], kfh, sa[m][ns]);
                }
            }
        }
        // write partials [qhh][dw][kv][q(44)]
        for (int m = 0; m < 2; ++m)
            for (int ns = 0; ns < 2; ++ns)
                *(f32x4*)(&par[(size_t)(((qhh * 4 + dw) * 32) + r + 16 * ns) * 44 + m * 16 + 4 * g]) = sa[m][ns];
        __syncthreads();
        // cross-wave reduce (each of the 4 d-waves redundantly, deterministic)
        f32x4 sf[2][2];
        for (int m = 0; m < 2; ++m)
            for (int ns = 0; ns < 2; ++ns) {
                int base = ((qhh * 4) * 32 + r + 16 * ns) * 44 + m * 16 + 4 * g;
                f32x4 v0 = *(const f32x4*)(&par[base]);
                f32x4 v1 = *(const f32x4*)(&par[base + 32 * 44]);
                f32x4 v2 = *(const f32x4*)(&par[base + 2 * 32 * 44]);
                f32x4 v3 = *(const f32x4*)(&par[base + 3 * 32 * 44]);
                sf[m][ns] = (v0 + v1) + (v2 + v3);
            }
        // online softmax (wave-parallel; rows live in 16-lane groups)
        float pv[2][2][4];
        for (int m = 0; m < 2; ++m) {
            for (int rg = 0; rg < 4; ++rg) {
                float tm = fmaxf(sf[m][0][rg], sf[m][1][rg]);
                for (int msk = 1; msk <= 8; msk <<= 1) tm = fmaxf(tm, __shfl_xor(tm, msk));
                float nm = fmaxf(runm[m][rg], tm);
                float sc = __expf(runm[m][rg] - nm);
                runm[m][rg] = nm;
                float p0 = __expf(sf[m][0][rg] - nm);
                float p1 = __expf(sf[m][1][rg] - nm);
                pv[m][0][rg] = p0; pv[m][1][rg] = p1;
                float rs = p0 + p1;
                for (int msk = 1; msk <= 8; msk <<= 1) rs += __shfl_xor(rs, msk);
                runl[m][rg] = runl[m][rg] * sc + rs;
                for (int ns = 0; ns < 8; ++ns) o[m][ns][rg] *= sc;
            }
        }
        // write P (bf16) to LDS in A-layout; each d-wave writes its (m,ns) quadrant
        {
            int mw_ = dw >> 1, nsw = dw & 1;
            for (int rg = 0; rg < 4; ++rg)
                p_s[qhh * (32 * 40) + (mw_ * 16 + 4 * g + rg) * 40 + r + 16 * nsw] =
                    f2bf(pv[mw_][nsw][rg]);
        }
        __syncthreads();
        // PV on this wave's 128-d chunk
        short8 pa[2];
        for (int m = 0; m < 2; ++m)
            pa[m] = *(const short8*)(&p_s[qhh * (32 * 40) + (m * 16 + r) * 40 + g * 8]);
        for (int ns = 0; ns < 8; ++ns) {
            const short8 vb = *(const short8*)(&vt_s[(dw * 128 + ns * 16 + r) * 40 + g * 8]);
            for (int m = 0; m < 2; ++m) o[m][ns] = MFMA(pa[m], vb, o[m][ns]);
        }
    }

    // epilogue: normalize and store fp32
    for (int m = 0; m < 2; ++m) {
        float inv[4];
        for (int rg = 0; rg < 4; ++rg) inv[rg] = 1.0f / runl[m][rg];
        for (int ns = 0; ns < 8; ++ns) {
            int col = dw * 128 + ns * 16 + r;
            size_t rowb = (size_t)(nb * SEQ + q0 + qhh * 32 + m * 16 + 4 * g);
            for (int rg = 0; rg < 4; ++rg)
                out[(rowb + rg) * 512 + col] = o[m][ns][rg] * inv[rg];
        }
    }
}

// ---------------------------------------------------------------------------
extern "C" void kernel_launch(void* const* d_in, const int* in_sizes, int n_in,
                              void* d_out, int out_size, void* d_ws, size_t ws_size,
                              hipStream_t stream) {
    const float* x  = (const float*)d_in[0];
    const float* Wq = (const float*)d_in[1];
    const float* bq = (const float*)d_in[2];
    const float* Wk = (const float*)d_in[3];
    const float* bk = (const float*)d_in[4];
    const float* Wv = (const float*)d_in[5];
    const float* bv = (const float*)d_in[6];
    float* out = (float*)d_out;

    char* ws = (char*)d_ws;
    const size_t QSZ = 16777216;                  // 16384*512*2B
    unsigned short* wth = (unsigned short*)(ws);
    unsigned short* wtl = (unsigned short*)(ws + 1572864);
    unsigned short* qh  = (unsigned short*)(ws + 3145728);
    unsigned short* ql  = (unsigned short*)(ws + 3145728 + 1 * QSZ);
    unsigned short* kh  = (unsigned short*)(ws + 3145728 + 2 * QSZ);
    unsigned short* kl  = (unsigned short*)(ws + 3145728 + 3 * QSZ);
    unsigned short* vt  = (unsigned short*)(ws + 3145728 + 4 * QSZ);

    k0_split_w<<<3072, 256, 0, stream>>>(Wq, Wk, Wv, wth, wtl);
    k1_proj<<<dim3(128, 4, 3), 256, 0, stream>>>(x, wth, wtl, bq, bk, bv,
                                                 qh, ql, kh, kl, vt);
    hipFuncSetAttribute((const void*)k2_attn,
                        hipFuncAttributeMaxDynamicSharedMemorySize, SMEM_K2);
    k2_attn<<<dim3(32, 8), 512, SMEM_K2, stream>>>(qh, ql, kh, kl, vt, out);
}

// Round 2
// 272.193 us; speedup vs baseline: 1.6748x; 1.6748x over previous
//
#include <hip/hip_runtime.h>
#include <hip/hip_bf16.h>
#include <hip/hip_fp16.h>

#define SEQ 2048
#define DIM 512

typedef __attribute__((ext_vector_type(8))) short short8;
typedef __attribute__((ext_vector_type(4))) float f32x4;
typedef _Float16 h8 __attribute__((ext_vector_type(8)));
typedef _Float16 h4 __attribute__((ext_vector_type(4)));

#define MFMA16(a, b, c) __builtin_amdgcn_mfma_f32_16x16x32_f16((a), (b), (c), 0, 0, 0)

// ---------------- K0a: split W -> f16 hi/lo, transposed to [n][k] ----------
__global__ __launch_bounds__(256) void k0a_splitw(
    const float* __restrict__ Wq, const float* __restrict__ Wk, const float* __restrict__ Wv,
    _Float16* __restrict__ wh, _Float16* __restrict__ wl) {
    int idx = blockIdx.x * 256 + threadIdx.x;   // [0, 3*512*512)
    int p = idx >> 18;
    int rem = idx & 262143;
    int k = rem >> 9, n = rem & 511;
    const float* W = (p == 0) ? Wq : (p == 1) ? Wk : Wv;
    float w = W[rem];
    _Float16 h = (_Float16)w;
    wh[(p << 18) + (n << 9) + k] = h;
    wl[(p << 18) + (n << 9) + k] = (_Float16)(w - (float)h);
}

// ---------------- K0b: x -> f16 (hi only) ----------------------------------
__global__ __launch_bounds__(256) void k0b_splitx(
    const float* __restrict__ x, _Float16* __restrict__ xh) {
    size_t i = (size_t)(blockIdx.x * 256 + threadIdx.x) * 4;
    float4 v = *(const float4*)(x + i);
    h4 h;
    h[0] = (_Float16)v.x; h[1] = (_Float16)v.y;
    h[2] = (_Float16)v.z; h[3] = (_Float16)v.w;
    *(h4*)(xh + i) = h;
}

// ---------------- shared GEMM helpers --------------------------------------
__device__ __forceinline__ void stage_tile(const _Float16* __restrict__ base, int pitch,
                                           int k0, _Float16* lds, int tid) {
    // [128 rows][32 k] -> lds [128][40]
    for (int j = 0; j < 2; ++j) {
        int c = tid + 256 * j;
        int row = c >> 2, slot = c & 3;
        *(short8*)(&lds[row * 40 + slot * 8]) =
            *(const short8*)(base + (size_t)row * pitch + k0 + slot * 8);
    }
}
__device__ __forceinline__ h8 frag(const _Float16* lds, int row, int g) {
    return *(const h8*)(&lds[row * 40 + g * 8]);
}

// ---------------- K1: projections: C = xh*(Wh+Wl) + b -----------------------
__global__ __launch_bounds__(256) void k1_proj(
    const _Float16* __restrict__ xh, const _Float16* __restrict__ wh,
    const _Float16* __restrict__ wl,
    const float* __restrict__ bq, const float* __restrict__ bk, const float* __restrict__ bv,
    _Float16* __restrict__ qh, _Float16* __restrict__ ql,
    _Float16* __restrict__ kh, _Float16* __restrict__ vt) {
    __shared__ _Float16 at[128 * 40], bht[128 * 40], blt[128 * 40];
    int tid = threadIdx.x;
    int m0 = blockIdx.x * 128, n0 = blockIdx.y * 128, p = blockIdx.z;
    const _Float16* wbh = wh + (p << 18) + (size_t)n0 * 512;
    const _Float16* wbl = wl + (p << 18) + (size_t)n0 * 512;
    const _Float16* ab = xh + (size_t)m0 * 512;
    const float* bias = (p == 0) ? bq : (p == 1) ? bk : bv;
    int wid = tid >> 6, lane = tid & 63, r = lane & 15, g = lane >> 4;
    int mw = wid >> 1, nw = wid & 1;

    f32x4 acc[4][4];
    for (int m = 0; m < 4; ++m)
        for (int n = 0; n < 4; ++n) acc[m][n] = (f32x4)(0.0f);

    for (int kt = 0; kt < 16; ++kt) {
        int k0 = kt * 32;
        __syncthreads();
        stage_tile(ab, 512, k0, at, tid);
        stage_tile(wbh, 512, k0, bht, tid);
        stage_tile(wbl, 512, k0, blt, tid);
        __syncthreads();
        h8 af[4], bfh[4], bfl[4];
        for (int m = 0; m < 4; ++m) af[m] = frag(at, mw * 64 + m * 16 + r, g);
        for (int n = 0; n < 4; ++n) {
            bfh[n] = frag(bht, nw * 64 + n * 16 + r, g);
            bfl[n] = frag(blt, nw * 64 + n * 16 + r, g);
        }
        for (int m = 0; m < 4; ++m)
            for (int n = 0; n < 4; ++n) {
                acc[m][n] = MFMA16(af[m], bfh[n], acc[m][n]);
                acc[m][n] = MFMA16(af[m], bfl[n], acc[m][n]);
            }
    }

    for (int n = 0; n < 4; ++n) {
        int col = n0 + nw * 64 + n * 16 + r;
        float bi = bias[col];
        for (int m = 0; m < 4; ++m) {
            int grow0 = m0 + mw * 64 + m * 16 + 4 * g;
            if (p == 0) {
                for (int reg = 0; reg < 4; ++reg) {
                    float val = acc[m][n][reg] + bi;
                    _Float16 h = (_Float16)val;
                    qh[(size_t)(grow0 + reg) * 512 + col] = h;
                    ql[(size_t)(grow0 + reg) * 512 + col] = (_Float16)(val - (float)h);
                }
            } else if (p == 1) {
                for (int reg = 0; reg < 4; ++reg)
                    kh[(size_t)(grow0 + reg) * 512 + col] = (_Float16)(acc[m][n][reg] + bi);
            } else {
                int b = grow0 >> 11, s0 = grow0 & 2047;
                h4 pv;
                pv[0] = (_Float16)(acc[m][n][0] + bi);
                pv[1] = (_Float16)(acc[m][n][1] + bi);
                pv[2] = (_Float16)(acc[m][n][2] + bi);
                pv[3] = (_Float16)(acc[m][n][3] + bi);
                *(h4*)(&vt[(size_t)b * (512 * 2048) + (size_t)col * 2048 + s0]) = pv;
            }
        }
    }
}

// ---------------- K2: S = (Qh+Ql) * Kh^T, fp32 out --------------------------
__global__ __launch_bounds__(256) void k2_qk(
    const _Float16* __restrict__ qh, const _Float16* __restrict__ ql,
    const _Float16* __restrict__ kh, float* __restrict__ sbuf, int bat0) {
    __shared__ _Float16 ath[128 * 40], atl[128 * 40], bt[128 * 40];
    int tid = threadIdx.x;
    int m0 = blockIdx.x * 128, n0 = blockIdx.y * 128, bz = blockIdx.z;
    int b = bat0 + bz;
    const _Float16* abh = qh + (size_t)b * (SEQ * 512) + (size_t)m0 * 512;
    const _Float16* abl = ql + (size_t)b * (SEQ * 512) + (size_t)m0 * 512;
    const _Float16* bb  = kh + (size_t)b * (SEQ * 512) + (size_t)n0 * 512;
    int wid = tid >> 6, lane = tid & 63, r = lane & 15, g = lane >> 4;
    int mw = wid >> 1, nw = wid & 1;

    f32x4 acc[4][4];
    for (int m = 0; m < 4; ++m)
        for (int n = 0; n < 4; ++n) acc[m][n] = (f32x4)(0.0f);

    for (int kt = 0; kt < 16; ++kt) {
        int k0 = kt * 32;
        __syncthreads();
        stage_tile(abh, 512, k0, ath, tid);
        stage_tile(abl, 512, k0, atl, tid);
        stage_tile(bb, 512, k0, bt, tid);
        __syncthreads();
        h8 afh[4], afl[4], bf[4];
        for (int m = 0; m < 4; ++m) {
            afh[m] = frag(ath, mw * 64 + m * 16 + r, g);
            afl[m] = frag(atl, mw * 64 + m * 16 + r, g);
        }
        for (int n = 0; n < 4; ++n) bf[n] = frag(bt, nw * 64 + n * 16 + r, g);
        for (int m = 0; m < 4; ++m)
            for (int n = 0; n < 4; ++n) {
                acc[m][n] = MFMA16(afh[m], bf[n], acc[m][n]);
                acc[m][n] = MFMA16(afl[m], bf[n], acc[m][n]);
            }
    }

    float* sb = sbuf + (size_t)bz * (SEQ * (size_t)SEQ);
    for (int n = 0; n < 4; ++n) {
        int col = n0 + nw * 64 + n * 16 + r;
        for (int m = 0; m < 4; ++m) {
            int grow0 = m0 + mw * 64 + m * 16 + 4 * g;
            for (int reg = 0; reg < 4; ++reg)
                sb[(size_t)(grow0 + reg) * SEQ + col] = acc[m][n][reg];
        }
    }
}

// ---------------- K3: row softmax, in-place P(f16) over S(f32) --------------
__global__ __launch_bounds__(256) void k3_softmax(float* __restrict__ sbuf) {
    size_t row = blockIdx.x;
    float* srow = sbuf + row * SEQ;
    int tid = threadIdx.x, lane = tid & 63, wid = tid >> 6;
    float4 v0 = *(const float4*)(srow + tid * 8);
    float4 v1 = *(const float4*)(srow + tid * 8 + 4);
    float m = fmaxf(fmaxf(fmaxf(v0.x, v0.y), fmaxf(v0.z, v0.w)),
                    fmaxf(fmaxf(v1.x, v1.y), fmaxf(v1.z, v1.w)));
    for (int d = 1; d < 64; d <<= 1) m = fmaxf(m, __shfl_xor(m, d));
    __shared__ float red1[4], red2[4];
    if (lane == 0) red1[wid] = m;
    __syncthreads();
    m = fmaxf(fmaxf(red1[0], red1[1]), fmaxf(red1[2], red1[3]));
    float e[8];
    e[0] = __expf(v0.x - m); e[1] = __expf(v0.y - m);
    e[2] = __expf(v0.z - m); e[3] = __expf(v0.w - m);
    e[4] = __expf(v1.x - m); e[5] = __expf(v1.y - m);
    e[6] = __expf(v1.z - m); e[7] = __expf(v1.w - m);
    float s = ((e[0] + e[1]) + (e[2] + e[3])) + ((e[4] + e[5]) + (e[6] + e[7]));
    for (int d = 1; d < 64; d <<= 1) s += __shfl_xor(s, d);
    if (lane == 0) red2[wid] = s;
    __syncthreads();
    s = (red2[0] + red2[1]) + (red2[2] + red2[3]);
    float inv = 1.0f / s;
    h8 ph;
    for (int j = 0; j < 8; ++j) ph[j] = (_Float16)(e[j] * inv);
    *(h8*)((char*)srow + (size_t)tid * 16) = ph;   // P row: first 4KB of S row
}

// ---------------- K4: out = P * V  (B = V^T [d][t]) -------------------------
__global__ __launch_bounds__(256) void k4_pv(
    const _Float16* __restrict__ pbuf,   // chunk base, row pitch 4096 f16
    const _Float16* __restrict__ vt, float* __restrict__ out, int bat0) {
    __shared__ _Float16 at[128 * 40], bt[128 * 40];
    int tid = threadIdx.x;
    int m0 = blockIdx.x * 128, n0 = blockIdx.y * 128, bz = blockIdx.z;
    int b = bat0 + bz;
    const _Float16* ab = pbuf + (size_t)bz * (SEQ * 4096) + (size_t)m0 * 4096;
    const _Float16* bb = vt + (size_t)b * (512 * SEQ) + (size_t)n0 * SEQ;
    int wid = tid >> 6, lane = tid & 63, r = lane & 15, g = lane >> 4;
    int mw = wid >> 1, nw = wid & 1;

    f32x4 acc[4][4];
    for (int m = 0; m < 4; ++m)
        for (int n = 0; n < 4; ++n) acc[m][n] = (f32x4)(0.0f);

    for (int kt = 0; kt < 64; ++kt) {
        int k0 = kt * 32;
        __syncthreads();
        stage_tile(ab, 4096, k0, at, tid);
        stage_tile(bb, SEQ, k0, bt, tid);
        __syncthreads();
        h8 af[4], bf[4];
        for (int m = 0; m < 4; ++m) af[m] = frag(at, mw * 64 + m * 16 + r, g);
        for (int n = 0; n < 4; ++n) bf[n] = frag(bt, nw * 64 + n * 16 + r, g);
        for (int m = 0; m < 4; ++m)
            for (int n = 0; n < 4; ++n)
                acc[m][n] = MFMA16(af[m], bf[n], acc[m][n]);
    }

    for (int n = 0; n < 4; ++n) {
        int col = n0 + nw * 64 + n * 16 + r;
        for (int m = 0; m < 4; ++m) {
            int grow0 = m0 + mw * 64 + m * 16 + 4 * g;
            for (int reg = 0; reg < 4; ++reg)
                out[(size_t)(b * SEQ + grow0 + reg) * 512 + col] = acc[m][n][reg];
        }
    }
}

// ---------------------------------------------------------------------------
extern "C" void kernel_launch(void* const* d_in, const int* in_sizes, int n_in,
                              void* d_out, int out_size, void* d_ws, size_t ws_size,
                              hipStream_t stream) {
    const float* x  = (const float*)d_in[0];
    const float* Wq = (const float*)d_in[1];
    const float* bq = (const float*)d_in[2];
    const float* Wk = (const float*)d_in[3];
    const float* bk = (const float*)d_in[4];
    const float* Wv = (const float*)d_in[5];
    const float* bv = (const float*)d_in[6];
    float* out = (float*)d_out;

    char* ws = (char*)d_ws;
    const size_t QSZ = 16777216;   // 16384*512*2B (also = one batch of S fp32)
    _Float16* wh = (_Float16*)(ws);
    _Float16* wl = (_Float16*)(ws + 1572864);
    _Float16* xh = (_Float16*)(ws + 3145728);
    _Float16* qh = (_Float16*)(ws + 3145728 + 1 * QSZ);
    _Float16* ql = (_Float16*)(ws + 3145728 + 2 * QSZ);
    _Float16* kh = (_Float16*)(ws + 3145728 + 3 * QSZ);
    _Float16* vt = (_Float16*)(ws + 3145728 + 4 * QSZ);
    const size_t sbase = 3145728 + 5 * QSZ;          // 87,031,808

    k0a_splitw<<<3072, 256, 0, stream>>>(Wq, Wk, Wv, wh, wl);
    k0b_splitx<<<8192, 256, 0, stream>>>(x, xh);
    k1_proj<<<dim3(128, 4, 3), 256, 0, stream>>>(xh, wh, wl, bq, bk, bv,
                                                 qh, ql, kh, vt);

    size_t avail = (ws_size > sbase) ? (ws_size - sbase) : 0;
    int chunk = (int)(avail / QSZ);
    if (chunk < 1) chunk = 1;
    if (chunk > 8) chunk = 8;
    float* sc = (float*)(ws + sbase);
    for (int b0 = 0; b0 < 8; b0 += chunk) {
        int nb = (8 - b0 < chunk) ? (8 - b0) : chunk;
        k2_qk<<<dim3(16, 16, nb), 256, 0, stream>>>(qh, ql, kh, sc, b0);
        k3_softmax<<<dim3(nb * SEQ), 256, 0, stream>>>(sc);
        k4_pv<<<dim3(16, 4, nb), 256, 0, stream>>>((const _Float16*)sc, vt, out, b0);
    }
}

// Round 3
// 253.856 us; speedup vs baseline: 1.7958x; 1.0722x over previous
//
#include <hip/hip_runtime.h>
#include <hip/hip_fp16.h>

#define SEQ 2048
#define DIM 512

typedef __attribute__((ext_vector_type(8))) short short8;
typedef __attribute__((ext_vector_type(4))) float f32x4;
typedef _Float16 h8 __attribute__((ext_vector_type(8)));
typedef _Float16 h4 __attribute__((ext_vector_type(4)));

#define MFMA16(a, b, c) __builtin_amdgcn_mfma_f32_16x16x32_f16((a), (b), (c), 0, 0, 0)

#define GLOAD_LDS16(g, l)                                                              \
    __builtin_amdgcn_global_load_lds(                                                  \
        (const __attribute__((address_space(1))) unsigned int*)(g),                    \
        (__attribute__((address_space(3))) unsigned int*)(l), 16, 0, 0)

// ---- async-stage one 128x32 f16 tile (8KB) into linear LDS ----------------
// Read-side XOR swizzle is pre-applied to the global source column so the
// ds_read side can use the same XOR (both-sides-or-neither, rule #21).
__device__ __forceinline__ void stage_g2l(const _Float16* __restrict__ gbase, int pitch_h,
                                          _Float16* lds, int wid, int lane) {
#pragma unroll
    for (int j = 0; j < 2; ++j) {
        int c = (j * 4 + wid) * 64 + lane;
        int row = c >> 2, s = c & 3;
        int col16 = s ^ ((row >> 1) & 3);
        const char* g = (const char*)gbase + (size_t)row * (pitch_h * 2) + col16 * 16;
        char* l = (char*)lds + (j * 4 + wid) * 1024;
        GLOAD_LDS16(g, l);
    }
}
__device__ __forceinline__ h8 fragswz(const _Float16* lds, int row, int g) {
    int g2 = g ^ ((row >> 1) & 3);
    return *(const h8*)((const char*)lds + row * 64 + g2 * 16);
}

// ---------------- K0a: split W -> f16 hi/lo, transposed to [n][k] ----------
__global__ __launch_bounds__(256) void k0a_splitw(
    const float* __restrict__ Wq, const float* __restrict__ Wk, const float* __restrict__ Wv,
    _Float16* __restrict__ wh, _Float16* __restrict__ wl) {
    int idx = blockIdx.x * 256 + threadIdx.x;   // [0, 3*512*512)
    int p = idx >> 18;
    int rem = idx & 262143;
    int k = rem >> 9, n = rem & 511;
    const float* W = (p == 0) ? Wq : (p == 1) ? Wk : Wv;
    float w = W[rem];
    _Float16 h = (_Float16)w;
    wh[(p << 18) + (n << 9) + k] = h;
    wl[(p << 18) + (n << 9) + k] = (_Float16)(w - (float)h);
}

// ---------------- K0b: x -> f16 ---------------------------------------------
__global__ __launch_bounds__(256) void k0b_splitx(
    const float* __restrict__ x, _Float16* __restrict__ xh) {
    size_t i = (size_t)(blockIdx.x * 256 + threadIdx.x) * 4;
    float4 v = *(const float4*)(x + i);
    h4 h;
    h[0] = (_Float16)v.x; h[1] = (_Float16)v.y;
    h[2] = (_Float16)v.z; h[3] = (_Float16)v.w;
    *(h4*)(xh + i) = h;
}

// ---------------- K1: projections: C = xh*(Wh+Wl) + b -----------------------
__global__ __launch_bounds__(256) void k1_proj(
    const _Float16* __restrict__ xh, const _Float16* __restrict__ wh,
    const _Float16* __restrict__ wl,
    const float* __restrict__ bq, const float* __restrict__ bk, const float* __restrict__ bv,
    _Float16* __restrict__ qh, _Float16* __restrict__ ql,
    _Float16* __restrict__ kh, _Float16* __restrict__ vt) {
    __shared__ _Float16 at[128 * 32], bht[128 * 32], blt[128 * 32];
    int tid = threadIdx.x;
    int m0 = blockIdx.x * 128, n0 = blockIdx.y * 128, p = blockIdx.z;
    const _Float16* wbh = wh + (p << 18) + (size_t)n0 * 512;
    const _Float16* wbl = wl + (p << 18) + (size_t)n0 * 512;
    const _Float16* ab = xh + (size_t)m0 * 512;
    const float* bias = (p == 0) ? bq : (p == 1) ? bk : bv;
    int wid = tid >> 6, lane = tid & 63, r = lane & 15, g = lane >> 4;
    int mw = wid >> 1, nw = wid & 1;

    f32x4 acc[4][4];
    for (int m = 0; m < 4; ++m)
        for (int n = 0; n < 4; ++n) acc[m][n] = (f32x4)(0.0f);

    for (int kt = 0; kt < 16; ++kt) {
        int k0 = kt * 32;
        __syncthreads();
        stage_g2l(ab + k0, 512, at, wid, lane);
        stage_g2l(wbh + k0, 512, bht, wid, lane);
        stage_g2l(wbl + k0, 512, blt, wid, lane);
        __syncthreads();
        h8 af[4], bfh[4], bfl[4];
#pragma unroll
        for (int m = 0; m < 4; ++m) af[m] = fragswz(at, mw * 64 + m * 16 + r, g);
#pragma unroll
        for (int n = 0; n < 4; ++n) {
            bfh[n] = fragswz(bht, nw * 64 + n * 16 + r, g);
            bfl[n] = fragswz(blt, nw * 64 + n * 16 + r, g);
        }
#pragma unroll
        for (int m = 0; m < 4; ++m)
#pragma unroll
            for (int n = 0; n < 4; ++n) {
                acc[m][n] = MFMA16(af[m], bfh[n], acc[m][n]);
                acc[m][n] = MFMA16(af[m], bfl[n], acc[m][n]);
            }
    }

    for (int n = 0; n < 4; ++n) {
        int col = n0 + nw * 64 + n * 16 + r;
        float bi = bias[col];
        for (int m = 0; m < 4; ++m) {
            int grow0 = m0 + mw * 64 + m * 16 + 4 * g;
            if (p == 0) {
                for (int reg = 0; reg < 4; ++reg) {
                    float val = acc[m][n][reg] + bi;
                    _Float16 h = (_Float16)val;
                    qh[(size_t)(grow0 + reg) * 512 + col] = h;
                    ql[(size_t)(grow0 + reg) * 512 + col] = (_Float16)(val - (float)h);
                }
            } else if (p == 1) {
                for (int reg = 0; reg < 4; ++reg)
                    kh[(size_t)(grow0 + reg) * 512 + col] = (_Float16)(acc[m][n][reg] + bi);
            } else {
                int b = grow0 >> 11, s0 = grow0 & 2047;
                h4 pv;
                pv[0] = (_Float16)(acc[m][n][0] + bi);
                pv[1] = (_Float16)(acc[m][n][1] + bi);
                pv[2] = (_Float16)(acc[m][n][2] + bi);
                pv[3] = (_Float16)(acc[m][n][3] + bi);
                *(h4*)(&vt[(size_t)b * (512 * 2048) + (size_t)col * 2048 + s0]) = pv;
            }
        }
    }
}

// ---------------- K2: S = (Qh+Ql) * Kh^T, fp32 out --------------------------
__global__ __launch_bounds__(256) void k2_qk(
    const _Float16* __restrict__ qh, const _Float16* __restrict__ ql,
    const _Float16* __restrict__ kh, float* __restrict__ sbuf, int bat0) {
    __shared__ _Float16 ath[128 * 32], atl[128 * 32], bt[128 * 32];
    int tid = threadIdx.x;
    int m0 = blockIdx.x * 128, n0 = blockIdx.y * 128, bz = blockIdx.z;
    int b = bat0 + bz;
    const _Float16* abh = qh + (size_t)b * (SEQ * 512) + (size_t)m0 * 512;
    const _Float16* abl = ql + (size_t)b * (SEQ * 512) + (size_t)m0 * 512;
    const _Float16* bb  = kh + (size_t)b * (SEQ * 512) + (size_t)n0 * 512;
    int wid = tid >> 6, lane = tid & 63, r = lane & 15, g = lane >> 4;
    int mw = wid >> 1, nw = wid & 1;

    f32x4 acc[4][4];
    for (int m = 0; m < 4; ++m)
        for (int n = 0; n < 4; ++n) acc[m][n] = (f32x4)(0.0f);

    for (int kt = 0; kt < 16; ++kt) {
        int k0 = kt * 32;
        __syncthreads();
        stage_g2l(abh + k0, 512, ath, wid, lane);
        stage_g2l(abl + k0, 512, atl, wid, lane);
        stage_g2l(bb + k0, 512, bt, wid, lane);
        __syncthreads();
        h8 afh[4], afl[4], bf[4];
#pragma unroll
        for (int m = 0; m < 4; ++m) {
            afh[m] = fragswz(ath, mw * 64 + m * 16 + r, g);
            afl[m] = fragswz(atl, mw * 64 + m * 16 + r, g);
        }
#pragma unroll
        for (int n = 0; n < 4; ++n) bf[n] = fragswz(bt, nw * 64 + n * 16 + r, g);
#pragma unroll
        for (int m = 0; m < 4; ++m)
#pragma unroll
            for (int n = 0; n < 4; ++n) {
                acc[m][n] = MFMA16(afh[m], bf[n], acc[m][n]);
                acc[m][n] = MFMA16(afl[m], bf[n], acc[m][n]);
            }
    }

    float* sb = sbuf + (size_t)bz * (SEQ * (size_t)SEQ);
    for (int n = 0; n < 4; ++n) {
        int col = n0 + nw * 64 + n * 16 + r;
        for (int m = 0; m < 4; ++m) {
            int grow0 = m0 + mw * 64 + m * 16 + 4 * g;
            for (int reg = 0; reg < 4; ++reg)
                sb[(size_t)(grow0 + reg) * SEQ + col] = acc[m][n][reg];
        }
    }
}

// ---------------- K3: row softmax, in-place P(f16) over S(f32) --------------
__global__ __launch_bounds__(256) void k3_softmax(float* __restrict__ sbuf) {
    size_t row = blockIdx.x;
    float* srow = sbuf + row * SEQ;
    int tid = threadIdx.x, lane = tid & 63, wid = tid >> 6;
    float4 v0 = *(const float4*)(srow + tid * 8);
    float4 v1 = *(const float4*)(srow + tid * 8 + 4);
    float m = fmaxf(fmaxf(fmaxf(v0.x, v0.y), fmaxf(v0.z, v0.w)),
                    fmaxf(fmaxf(v1.x, v1.y), fmaxf(v1.z, v1.w)));
    for (int d = 1; d < 64; d <<= 1) m = fmaxf(m, __shfl_xor(m, d));
    __shared__ float red1[4], red2[4];
    if (lane == 0) red1[wid] = m;
    __syncthreads();
    m = fmaxf(fmaxf(red1[0], red1[1]), fmaxf(red1[2], red1[3]));
    float e[8];
    e[0] = __expf(v0.x - m); e[1] = __expf(v0.y - m);
    e[2] = __expf(v0.z - m); e[3] = __expf(v0.w - m);
    e[4] = __expf(v1.x - m); e[5] = __expf(v1.y - m);
    e[6] = __expf(v1.z - m); e[7] = __expf(v1.w - m);
    float s = ((e[0] + e[1]) + (e[2] + e[3])) + ((e[4] + e[5]) + (e[6] + e[7]));
    for (int d = 1; d < 64; d <<= 1) s += __shfl_xor(s, d);
    if (lane == 0) red2[wid] = s;
    __syncthreads();
    s = (red2[0] + red2[1]) + (red2[2] + red2[3]);
    float inv = 1.0f / s;
    h8 ph;
    for (int j = 0; j < 8; ++j) ph[j] = (_Float16)(e[j] * inv);
    *(h8*)((char*)srow + (size_t)tid * 16) = ph;   // P row: first 4KB of S row
}

// ---------------- K4: out = P * V  (B = V^T [d][t]) -------------------------
__global__ __launch_bounds__(256) void k4_pv(
    const _Float16* __restrict__ pbuf,   // chunk base, row pitch 4096 f16
    const _Float16* __restrict__ vt, float* __restrict__ out, int bat0) {
    __shared__ _Float16 at[128 * 32], bt[128 * 32];
    int tid = threadIdx.x;
    int m0 = blockIdx.x * 128, n0 = blockIdx.y * 128, bz = blockIdx.z;
    int b = bat0 + bz;
    const _Float16* ab = pbuf + (size_t)bz * (SEQ * 4096) + (size_t)m0 * 4096;
    const _Float16* bb = vt + (size_t)b * (512 * SEQ) + (size_t)n0 * SEQ;
    int wid = tid >> 6, lane = tid & 63, r = lane & 15, g = lane >> 4;
    int mw = wid >> 1, nw = wid & 1;

    f32x4 acc[4][4];
    for (int m = 0; m < 4; ++m)
        for (int n = 0; n < 4; ++n) acc[m][n] = (f32x4)(0.0f);

    for (int kt = 0; kt < 64; ++kt) {
        int k0 = kt * 32;
        __syncthreads();
        stage_g2l(ab + k0, 4096, at, wid, lane);
        stage_g2l(bb + k0, SEQ, bt, wid, lane);
        __syncthreads();
        h8 af[4], bf[4];
#pragma unroll
        for (int m = 0; m < 4; ++m) af[m] = fragswz(at, mw * 64 + m * 16 + r, g);
#pragma unroll
        for (int n = 0; n < 4; ++n) bf[n] = fragswz(bt, nw * 64 + n * 16 + r, g);
#pragma unroll
        for (int m = 0; m < 4; ++m)
#pragma unroll
            for (int n = 0; n < 4; ++n)
                acc[m][n] = MFMA16(af[m], bf[n], acc[m][n]);
    }

    for (int n = 0; n < 4; ++n) {
        int col = n0 + nw * 64 + n * 16 + r;
        for (int m = 0; m < 4; ++m) {
            int grow0 = m0 + mw * 64 + m * 16 + 4 * g;
            for (int reg = 0; reg < 4; ++reg)
                out[(size_t)(b * SEQ + grow0 + reg) * 512 + col] = acc[m][n][reg];
        }
    }
}

// ---------------------------------------------------------------------------
extern "C" void kernel_launch(void* const* d_in, const int* in_sizes, int n_in,
                              void* d_out, int out_size, void* d_ws, size_t ws_size,
                              hipStream_t stream) {
    const float* x  = (const float*)d_in[0];
    const float* Wq = (const float*)d_in[1];
    const float* bq = (const float*)d_in[2];
    const float* Wk = (const float*)d_in[3];
    const float* bk = (const float*)d_in[4];
    const float* Wv = (const float*)d_in[5];
    const float* bv = (const float*)d_in[6];
    float* out = (float*)d_out;

    char* ws = (char*)d_ws;
    const size_t QSZ = 16777216;   // 16384*512*2B (also = one batch of S fp32)
    _Float16* wh = (_Float16*)(ws);
    _Float16* wl = (_Float16*)(ws + 1572864);
    _Float16* xh = (_Float16*)(ws + 3145728);
    _Float16* qh = (_Float16*)(ws + 3145728 + 1 * QSZ);
    _Float16* ql = (_Float16*)(ws + 3145728 + 2 * QSZ);
    _Float16* kh = (_Float16*)(ws + 3145728 + 3 * QSZ);
    _Float16* vt = (_Float16*)(ws + 3145728 + 4 * QSZ);
    const size_t sbase = 3145728 + 5 * QSZ;          // 87,031,808

    k0a_splitw<<<3072, 256, 0, stream>>>(Wq, Wk, Wv, wh, wl);
    k0b_splitx<<<8192, 256, 0, stream>>>(x, xh);
    k1_proj<<<dim3(128, 4, 3), 256, 0, stream>>>(xh, wh, wl, bq, bk, bv,
                                                 qh, ql, kh, vt);

    size_t avail = (ws_size > sbase) ? (ws_size - sbase) : 0;
    int chunk = (int)(avail / QSZ);
    if (chunk < 1) chunk = 1;
    if (chunk > 8) chunk = 8;
    float* sc = (float*)(ws + sbase);
    for (int b0 = 0; b0 < 8; b0 += chunk) {
        int nb = (8 - b0 < chunk) ? (8 - b0) : chunk;
        k2_qk<<<dim3(16, 16, nb), 256, 0, stream>>>(qh, ql, kh, sc, b0);
        k3_softmax<<<dim3(nb * SEQ), 256, 0, stream>>>(sc);
        k4_pv<<<dim3(16, 4, nb), 256, 0, stream>>>((const _Float16*)sc, vt, out, b0);
    }
}

// Round 4
// 234.415 us; speedup vs baseline: 1.9448x; 1.0829x over previous
//
#include <hip/hip_runtime.h>
#include <hip/hip_fp16.h>

#define SEQ 2048
#define DIM 512

typedef __attribute__((ext_vector_type(8))) short short8;
typedef __attribute__((ext_vector_type(4))) float f32x4;
typedef _Float16 h8 __attribute__((ext_vector_type(8)));
typedef _Float16 h4 __attribute__((ext_vector_type(4)));

#define MFMA16(a, b, c) __builtin_amdgcn_mfma_f32_16x16x32_f16((a), (b), (c), 0, 0, 0)

#define GLOAD_LDS16(g, l)                                                              \
    __builtin_amdgcn_global_load_lds(                                                  \
        (const __attribute__((address_space(1))) unsigned int*)(g),                    \
        (__attribute__((address_space(3))) unsigned int*)(l), 16, 0, 0)

// ---- async-stage one 128x32 f16 tile (8KB) into linear LDS ----------------
// Read-side XOR swizzle pre-applied to the global source column (rule #21).
__device__ __forceinline__ void stage_g2l(const _Float16* __restrict__ gbase, int pitch_h,
                                          _Float16* lds, int wid, int lane) {
#pragma unroll
    for (int j = 0; j < 2; ++j) {
        int c = (j * 4 + wid) * 64 + lane;
        int row = c >> 2, s = c & 3;
        int col16 = s ^ ((row >> 1) & 3);
        const char* g = (const char*)gbase + (size_t)row * (pitch_h * 2) + col16 * 16;
        char* l = (char*)lds + (j * 4 + wid) * 1024;
        GLOAD_LDS16(g, l);
    }
}
__device__ __forceinline__ h8 fragswz(const _Float16* lds, int row, int g) {
    int g2 = g ^ ((row >> 1) & 3);
    return *(const h8*)((const char*)lds + row * 64 + g2 * 16);
}

// ---------------- K0a: split W -> f16 hi/lo, transposed to [n][k] ----------
__global__ __launch_bounds__(256) void k0a_splitw(
    const float* __restrict__ Wq, const float* __restrict__ Wk, const float* __restrict__ Wv,
    _Float16* __restrict__ wh, _Float16* __restrict__ wl) {
    int idx = blockIdx.x * 256 + threadIdx.x;   // [0, 3*512*512)
    int p = idx >> 18;
    int rem = idx & 262143;
    int k = rem >> 9, n = rem & 511;
    const float* W = (p == 0) ? Wq : (p == 1) ? Wk : Wv;
    float w = W[rem];
    _Float16 h = (_Float16)w;
    wh[(p << 18) + (n << 9) + k] = h;
    wl[(p << 18) + (n << 9) + k] = (_Float16)(w - (float)h);
}

// ---------------- K0b: x -> f16 ---------------------------------------------
__global__ __launch_bounds__(256) void k0b_splitx(
    const float* __restrict__ x, _Float16* __restrict__ xh) {
    size_t i = (size_t)(blockIdx.x * 256 + threadIdx.x) * 4;
    float4 v = *(const float4*)(x + i);
    h4 h;
    h[0] = (_Float16)v.x; h[1] = (_Float16)v.y;
    h[2] = (_Float16)v.z; h[3] = (_Float16)v.w;
    *(h4*)(xh + i) = h;
}

// ---------------- K1: projections: C = xh*(Wh+Wl) + b, 2-phase pipelined ----
__global__ __launch_bounds__(256) void k1_proj(
    const _Float16* __restrict__ xh, const _Float16* __restrict__ wh,
    const _Float16* __restrict__ wl,
    const float* __restrict__ bq, const float* __restrict__ bk, const float* __restrict__ bv,
    _Float16* __restrict__ qh, _Float16* __restrict__ kh, _Float16* __restrict__ vt) {
    __shared__ _Float16 at[2][128 * 32], bht[2][128 * 32], blt[2][128 * 32];
    int tid = threadIdx.x;
    int m0 = blockIdx.x * 128, n0 = blockIdx.y * 128, p = blockIdx.z;
    const _Float16* wbh = wh + (p << 18) + (size_t)n0 * 512;
    const _Float16* wbl = wl + (p << 18) + (size_t)n0 * 512;
    const _Float16* ab = xh + (size_t)m0 * 512;
    const float* bias = (p == 0) ? bq : (p == 1) ? bk : bv;
    int wid = tid >> 6, lane = tid & 63, r = lane & 15, g = lane >> 4;
    int mw = wid >> 1, nw = wid & 1;

    f32x4 acc[4][4];
    for (int m = 0; m < 4; ++m)
        for (int n = 0; n < 4; ++n) acc[m][n] = (f32x4)(0.0f);

    // prologue: stage tile 0
    stage_g2l(ab, 512, at[0], wid, lane);
    stage_g2l(wbh, 512, bht[0], wid, lane);
    stage_g2l(wbl, 512, blt[0], wid, lane);
    __syncthreads();

    int cur = 0;
    for (int kt = 0; kt < 16; ++kt) {
        // issue next tile's loads first (latency hides under compute below)
        if (kt + 1 < 16) {
            int k1 = (kt + 1) * 32;
            stage_g2l(ab + k1, 512, at[cur ^ 1], wid, lane);
            stage_g2l(wbh + k1, 512, bht[cur ^ 1], wid, lane);
            stage_g2l(wbl + k1, 512, blt[cur ^ 1], wid, lane);
        }
        h8 af[4], bfh[4], bfl[4];
#pragma unroll
        for (int m = 0; m < 4; ++m) af[m] = fragswz(at[cur], mw * 64 + m * 16 + r, g);
#pragma unroll
        for (int n = 0; n < 4; ++n) {
            bfh[n] = fragswz(bht[cur], nw * 64 + n * 16 + r, g);
            bfl[n] = fragswz(blt[cur], nw * 64 + n * 16 + r, g);
        }
#pragma unroll
        for (int m = 0; m < 4; ++m)
#pragma unroll
            for (int n = 0; n < 4; ++n) {
                acc[m][n] = MFMA16(af[m], bfh[n], acc[m][n]);
                acc[m][n] = MFMA16(af[m], bfl[n], acc[m][n]);
            }
        __syncthreads();   // drains vmcnt(0): next tile landed
        cur ^= 1;
    }

    for (int n = 0; n < 4; ++n) {
        int col = n0 + nw * 64 + n * 16 + r;
        float bi = bias[col];
        for (int m = 0; m < 4; ++m) {
            int grow0 = m0 + mw * 64 + m * 16 + 4 * g;
            if (p < 2) {
                _Float16* dst = (p == 0) ? qh : kh;
                for (int reg = 0; reg < 4; ++reg)
                    dst[(size_t)(grow0 + reg) * 512 + col] = (_Float16)(acc[m][n][reg] + bi);
            } else {
                int b = grow0 >> 11, s0 = grow0 & 2047;
                h4 pv;
                pv[0] = (_Float16)(acc[m][n][0] + bi);
                pv[1] = (_Float16)(acc[m][n][1] + bi);
                pv[2] = (_Float16)(acc[m][n][2] + bi);
                pv[3] = (_Float16)(acc[m][n][3] + bi);
                *(h4*)(&vt[(size_t)b * (512 * 2048) + (size_t)col * 2048 + s0]) = pv;
            }
        }
    }
}

// ---------------- K2: S = Qh * Kh^T, fp32 out, 2-phase ----------------------
__global__ __launch_bounds__(256) void k2_qk(
    const _Float16* __restrict__ qh, const _Float16* __restrict__ kh,
    float* __restrict__ sbuf, int bat0) {
    __shared__ _Float16 ath[2][128 * 32], bt[2][128 * 32];
    int tid = threadIdx.x;
    int m0 = blockIdx.x * 128, n0 = blockIdx.y * 128, bz = blockIdx.z;
    int b = bat0 + bz;
    const _Float16* abh = qh + (size_t)b * (SEQ * 512) + (size_t)m0 * 512;
    const _Float16* bb  = kh + (size_t)b * (SEQ * 512) + (size_t)n0 * 512;
    int wid = tid >> 6, lane = tid & 63, r = lane & 15, g = lane >> 4;
    int mw = wid >> 1, nw = wid & 1;

    f32x4 acc[4][4];
    for (int m = 0; m < 4; ++m)
        for (int n = 0; n < 4; ++n) acc[m][n] = (f32x4)(0.0f);

    stage_g2l(abh, 512, ath[0], wid, lane);
    stage_g2l(bb, 512, bt[0], wid, lane);
    __syncthreads();

    int cur = 0;
    for (int kt = 0; kt < 16; ++kt) {
        if (kt + 1 < 16) {
            int k1 = (kt + 1) * 32;
            stage_g2l(abh + k1, 512, ath[cur ^ 1], wid, lane);
            stage_g2l(bb + k1, 512, bt[cur ^ 1], wid, lane);
        }
        h8 afh[4], bf[4];
#pragma unroll
        for (int m = 0; m < 4; ++m) afh[m] = fragswz(ath[cur], mw * 64 + m * 16 + r, g);
#pragma unroll
        for (int n = 0; n < 4; ++n) bf[n] = fragswz(bt[cur], nw * 64 + n * 16 + r, g);
#pragma unroll
        for (int m = 0; m < 4; ++m)
#pragma unroll
            for (int n = 0; n < 4; ++n)
                acc[m][n] = MFMA16(afh[m], bf[n], acc[m][n]);
        __syncthreads();
        cur ^= 1;
    }

    float* sb = sbuf + (size_t)bz * (SEQ * (size_t)SEQ);
    for (int n = 0; n < 4; ++n) {
        int col = n0 + nw * 64 + n * 16 + r;
        for (int m = 0; m < 4; ++m) {
            int grow0 = m0 + mw * 64 + m * 16 + 4 * g;
            for (int reg = 0; reg < 4; ++reg)
                sb[(size_t)(grow0 + reg) * SEQ + col] = acc[m][n][reg];
        }
    }
}

// ---------------- K3: row softmax, in-place P(f16) over S(f32) --------------
__global__ __launch_bounds__(256) void k3_softmax(float* __restrict__ sbuf) {
    size_t row = blockIdx.x;
    float* srow = sbuf + row * SEQ;
    int tid = threadIdx.x, lane = tid & 63, wid = tid >> 6;
    float4 v0 = *(const float4*)(srow + tid * 8);
    float4 v1 = *(const float4*)(srow + tid * 8 + 4);
    float m = fmaxf(fmaxf(fmaxf(v0.x, v0.y), fmaxf(v0.z, v0.w)),
                    fmaxf(fmaxf(v1.x, v1.y), fmaxf(v1.z, v1.w)));
    for (int d = 1; d < 64; d <<= 1) m = fmaxf(m, __shfl_xor(m, d));
    __shared__ float red1[4], red2[4];
    if (lane == 0) red1[wid] = m;
    __syncthreads();
    m = fmaxf(fmaxf(red1[0], red1[1]), fmaxf(red1[2], red1[3]));
    float e[8];
    e[0] = __expf(v0.x - m); e[1] = __expf(v0.y - m);
    e[2] = __expf(v0.z - m); e[3] = __expf(v0.w - m);
    e[4] = __expf(v1.x - m); e[5] = __expf(v1.y - m);
    e[6] = __expf(v1.z - m); e[7] = __expf(v1.w - m);
    float s = ((e[0] + e[1]) + (e[2] + e[3])) + ((e[4] + e[5]) + (e[6] + e[7]));
    for (int d = 1; d < 64; d <<= 1) s += __shfl_xor(s, d);
    if (lane == 0) red2[wid] = s;
    __syncthreads();
    s = (red2[0] + red2[1]) + (red2[2] + red2[3]);
    float inv = 1.0f / s;
    h8 ph;
    for (int j = 0; j < 8; ++j) ph[j] = (_Float16)(e[j] * inv);
    *(h8*)((char*)srow + (size_t)tid * 16) = ph;   // P row: first 4KB of S row
}

// ---------------- K4: out = P * V  (B = V^T [d][t]), 2-phase ----------------
__global__ __launch_bounds__(256) void k4_pv(
    const _Float16* __restrict__ pbuf,   // chunk base, row pitch 4096 f16
    const _Float16* __restrict__ vt, float* __restrict__ out, int bat0) {
    __shared__ _Float16 at[2][128 * 32], bt[2][128 * 32];
    int tid = threadIdx.x;
    int m0 = blockIdx.x * 128, n0 = blockIdx.y * 128, bz = blockIdx.z;
    int b = bat0 + bz;
    const _Float16* ab = pbuf + (size_t)bz * (SEQ * 4096) + (size_t)m0 * 4096;
    const _Float16* bb = vt + (size_t)b * (512 * SEQ) + (size_t)n0 * SEQ;
    int wid = tid >> 6, lane = tid & 63, r = lane & 15, g = lane >> 4;
    int mw = wid >> 1, nw = wid & 1;

    f32x4 acc[4][4];
    for (int m = 0; m < 4; ++m)
        for (int n = 0; n < 4; ++n) acc[m][n] = (f32x4)(0.0f);

    stage_g2l(ab, 4096, at[0], wid, lane);
    stage_g2l(bb, SEQ, bt[0], wid, lane);
    __syncthreads();

    int cur = 0;
    for (int kt = 0; kt < 64; ++kt) {
        if (kt + 1 < 64) {
            int k1 = (kt + 1) * 32;
            stage_g2l(ab + k1, 4096, at[cur ^ 1], wid, lane);
            stage_g2l(bb + k1, SEQ, bt[cur ^ 1], wid, lane);
        }
        h8 af[4], bf[4];
#pragma unroll
        for (int m = 0; m < 4; ++m) af[m] = fragswz(at[cur], mw * 64 + m * 16 + r, g);
#pragma unroll
        for (int n = 0; n < 4; ++n) bf[n] = fragswz(bt[cur], nw * 64 + n * 16 + r, g);
#pragma unroll
        for (int m = 0; m < 4; ++m)
#pragma unroll
            for (int n = 0; n < 4; ++n)
                acc[m][n] = MFMA16(af[m], bf[n], acc[m][n]);
        __syncthreads();
        cur ^= 1;
    }

    for (int n = 0; n < 4; ++n) {
        int col = n0 + nw * 64 + n * 16 + r;
        for (int m = 0; m < 4; ++m) {
            int grow0 = m0 + mw * 64 + m * 16 + 4 * g;
            for (int reg = 0; reg < 4; ++reg)
                out[(size_t)(b * SEQ + grow0 + reg) * 512 + col] = acc[m][n][reg];
        }
    }
}

// ---------------------------------------------------------------------------
extern "C" void kernel_launch(void* const* d_in, const int* in_sizes, int n_in,
                              void* d_out, int out_size, void* d_ws, size_t ws_size,
                              hipStream_t stream) {
    const float* x  = (const float*)d_in[0];
    const float* Wq = (const float*)d_in[1];
    const float* bq = (const float*)d_in[2];
    const float* Wk = (const float*)d_in[3];
    const float* bk = (const float*)d_in[4];
    const float* Wv = (const float*)d_in[5];
    const float* bv = (const float*)d_in[6];
    float* out = (float*)d_out;

    char* ws = (char*)d_ws;
    const size_t QSZ = 16777216;   // 16384*512*2B (also = one batch of S fp32)
    _Float16* wh = (_Float16*)(ws);
    _Float16* wl = (_Float16*)(ws + 1572864);
    _Float16* xh = (_Float16*)(ws + 3145728);
    _Float16* qh = (_Float16*)(ws + 3145728 + 1 * QSZ);
    _Float16* kh = (_Float16*)(ws + 3145728 + 2 * QSZ);
    _Float16* vt = (_Float16*)(ws + 3145728 + 3 * QSZ);
    const size_t sbase = 3145728 + 4 * QSZ;          // 70,254,592

    k0a_splitw<<<3072, 256, 0, stream>>>(Wq, Wk, Wv, wh, wl);
    k0b_splitx<<<8192, 256, 0, stream>>>(x, xh);
    k1_proj<<<dim3(128, 4, 3), 256, 0, stream>>>(xh, wh, wl, bq, bk, bv,
                                                 qh, kh, vt);

    size_t avail = (ws_size > sbase) ? (ws_size - sbase) : 0;
    int chunk = (int)(avail / QSZ);
    if (chunk < 1) chunk = 1;
    if (chunk > 8) chunk = 8;
    float* sc = (float*)(ws + sbase);
    for (int b0 = 0; b0 < 8; b0 += chunk) {
        int nb = (8 - b0 < chunk) ? (8 - b0) : chunk;
        k2_qk<<<dim3(16, 16, nb), 256, 0, stream>>>(qh, kh, sc, b0);
        k3_softmax<<<dim3(nb * SEQ), 256, 0, stream>>>(sc);
        k4_pv<<<dim3(16, 4, nb), 256, 0, stream>>>((const _Float16*)sc, vt, out, b0);
    }
}

// Round 5
// 229.259 us; speedup vs baseline: 1.9885x; 1.0225x over previous
//
#include <hip/hip_runtime.h>
#include <hip/hip_fp16.h>

#define SEQ 2048
#define DIM 512

typedef __attribute__((ext_vector_type(8))) short short8;
typedef __attribute__((ext_vector_type(4))) float f32x4;
typedef _Float16 h8 __attribute__((ext_vector_type(8)));
typedef _Float16 h4 __attribute__((ext_vector_type(4)));

#define MFMA16(a, b, c) __builtin_amdgcn_mfma_f32_16x16x32_f16((a), (b), (c), 0, 0, 0)

#define GLOAD_LDS16(g, l)                                                              \
    __builtin_amdgcn_global_load_lds(                                                  \
        (const __attribute__((address_space(1))) unsigned int*)(g),                    \
        (__attribute__((address_space(3))) unsigned int*)(l), 16, 0, 0)

#define BAR() __builtin_amdgcn_s_barrier()
#define WAITL()                                                                        \
    do {                                                                               \
        asm volatile("s_waitcnt lgkmcnt(0)" ::: "memory");                             \
        __builtin_amdgcn_sched_barrier(0);                                             \
    } while (0)

// ======================= 256x256 8-phase GEMM template ======================
// BM=BN=256, BK=64, 8 waves (2M x 4N), 512 threads, LDS 128KB.
// MODE 0: PROJ  C[16384,1536] = xh @ [Wh;Wl] (virtual K=1024), f16 out + bias
// MODE 1: QK    S[b][2048,2048] = Q @ K^T (K=512), fp32 out
template <int MODE>
__global__ __launch_bounds__(512, 1) void gemm256(
    const _Float16* __restrict__ A,
    const _Float16* __restrict__ Bh, const _Float16* __restrict__ Bl,
    const float* __restrict__ bq, const float* __restrict__ bk,
    const float* __restrict__ bv,
    _Float16* __restrict__ oq, _Float16* __restrict__ ok,
    _Float16* __restrict__ ovt, float* __restrict__ osc, int bat0) {
    extern __shared__ char lds[];
    constexpr int T = (MODE == 0) ? 16 : 8;

    int nwg = gridDim.x;
    int wg = blockIdx.x;
    int swz = (wg & 7) * (nwg >> 3) + (wg >> 3);   // XCD swizzle (nwg % 8 == 0)
    int bm, bn, brel = 0;
    if (MODE == 0) { bm = swz / 6; bn = swz % 6; }
    else { brel = swz >> 6; int tt = swz & 63; bm = tt >> 3; bn = tt & 7; }

    int tid = threadIdx.x;
    int wid = tid >> 6, lane = tid & 63, r = lane & 15, g = lane >> 4;
    int wm = wid >> 2, wn = wid & 3;

    const _Float16* Ab;
    const _Float16* Bb_h;
    const _Float16* Bb_l = nullptr;
    int nloc0 = 0;
    if (MODE == 0) {
        Ab = A + (size_t)bm * 256 * 512;
        int p = bn >> 1;
        nloc0 = (bn & 1) * 256;
        Bb_h = Bh + ((size_t)p << 18) + (size_t)nloc0 * 512;
        Bb_l = Bl + ((size_t)p << 18) + (size_t)nloc0 * 512;
    } else {
        int bat = bat0 + brel;
        Ab = A + ((size_t)(bat * SEQ) + bm * 256) * 512;
        Bb_h = Bh + ((size_t)(bat * SEQ) + bn * 256) * 512;
    }

    // stage one half-tile: part 0=A h0, 1=B h0, 2=A h1, 3=B h1 -> 16KB
    auto stage = [&](int tile, int part) {
        int cb = tile & 1;
        int hf = part >> 1, isB = part & 1;
        char* dst = lds + (isB ? 65536 : 0) + (cb * 2 + hf) * 16384 + wid * 2048;
        int k0 = (MODE == 0) ? ((tile & 7) * 64) : (tile * 64);
        const _Float16* srcb;
        if (MODE == 0) srcb = isB ? ((tile < 8) ? Bb_h : Bb_l) : Ab;
        else srcb = isB ? Bb_h : Ab;
#pragma unroll
        for (int j = 0; j < 2; ++j) {
            int ci = (wid * 2 + j) * 64 + lane;
            int row = ci >> 3;
            int ch = (ci & 7) ^ (row & 7);   // inverse swizzle on global source
            const _Float16* src = srcb + (size_t)(hf * 128 + row) * 512 + k0 + ch * 8;
            GLOAD_LDS16(src, dst + j * 1024);
        }
    };
    auto rdA = [&](int cb, int qA, h8 a[4][2]) {
        const char* base = lds + (cb * 2 + wm) * 16384;
#pragma unroll
        for (int m = 0; m < 4; ++m)
#pragma unroll
            for (int ks = 0; ks < 2; ++ks) {
                int row = qA * 64 + m * 16 + r;
                int ch = (ks * 4 + g) ^ (row & 7);
                a[m][ks] = *(const h8*)(base + row * 128 + ch * 16);
            }
    };
    auto rdB = [&](int cb, int qB, h8 b[2][2]) {
        const char* base = lds + 65536 + (cb * 2 + (wn >> 1)) * 16384;
#pragma unroll
        for (int n = 0; n < 2; ++n)
#pragma unroll
            for (int ks = 0; ks < 2; ++ks) {
                int row = (wn & 1) * 64 + qB * 32 + n * 16 + r;
                int ch = (ks * 4 + g) ^ (row & 7);
                b[n][ks] = *(const h8*)(base + row * 128 + ch * 16);
            }
    };

    f32x4 acc[8][4];
#pragma unroll
    for (int m = 0; m < 8; ++m)
#pragma unroll
        for (int n = 0; n < 4; ++n) acc[m][n] = (f32x4)(0.0f);

    // prologue: stage tiles 0 (buf0) and 1 (buf1); tile0 must be landed
#pragma unroll
    for (int t0 = 0; t0 < 2; ++t0)
#pragma unroll
        for (int p0 = 0; p0 < 4; ++p0) stage(t0, p0);
    asm volatile("s_waitcnt vmcnt(8)" ::: "memory");
    BAR();

    h8 a[4][2], b0[2][2], b1[2][2];
    for (int t = 0; t < T; ++t) {
        int cb = t & 1;
        // ---- q0: (qA=0, qB=0) ----
        rdA(cb, 0, a);
        rdB(cb, 0, b0);
        BAR();
        WAITL();
        __builtin_amdgcn_s_setprio(1);
#pragma unroll
        for (int ks = 0; ks < 2; ++ks)
#pragma unroll
            for (int m = 0; m < 4; ++m)
#pragma unroll
                for (int n = 0; n < 2; ++n)
                    acc[m][n] = MFMA16(a[m][ks], b0[n][ks], acc[m][n]);
        __builtin_amdgcn_s_setprio(0);
        BAR();
        // ---- q1: (qA=0, qB=1) ----
        rdB(cb, 1, b1);
        BAR();
        WAITL();
        __builtin_amdgcn_s_setprio(1);
#pragma unroll
        for (int ks = 0; ks < 2; ++ks)
#pragma unroll
            for (int m = 0; m < 4; ++m)
#pragma unroll
                for (int n = 0; n < 2; ++n)
                    acc[m][2 + n] = MFMA16(a[m][ks], b1[n][ks], acc[m][2 + n]);
        __builtin_amdgcn_s_setprio(0);
        BAR();
        // ---- q2: (qA=1, qB=1); B regions free -> stage t+2's B halves ----
        rdA(cb, 1, a);
        if (t + 2 < T) { stage(t + 2, 1); stage(t + 2, 3); }
        BAR();
        WAITL();
        __builtin_amdgcn_s_setprio(1);
#pragma unroll
        for (int ks = 0; ks < 2; ++ks)
#pragma unroll
            for (int m = 0; m < 4; ++m)
#pragma unroll
                for (int n = 0; n < 2; ++n)
                    acc[4 + m][2 + n] = MFMA16(a[m][ks], b1[n][ks], acc[4 + m][2 + n]);
        __builtin_amdgcn_s_setprio(0);
        BAR();
        // ---- q3: (qA=1, qB=0); A regions free -> stage t+2's A halves ----
        if (t + 2 < T) { stage(t + 2, 0); stage(t + 2, 2); }
        BAR();
        WAITL();
        __builtin_amdgcn_s_setprio(1);
#pragma unroll
        for (int ks = 0; ks < 2; ++ks)
#pragma unroll
            for (int m = 0; m < 4; ++m)
#pragma unroll
                for (int n = 0; n < 2; ++n)
                    acc[4 + m][n] = MFMA16(a[m][ks], b0[n][ks], acc[4 + m][n]);
        __builtin_amdgcn_s_setprio(0);
        if (t < T - 2) asm volatile("s_waitcnt vmcnt(8)" ::: "memory");
        else if (t == T - 2) asm volatile("s_waitcnt vmcnt(0)" ::: "memory");
        BAR();
    }

    // ---- epilogue ----
    int browbase = bm * 256 + wm * 128;
    if (MODE == 0) {
        int p = bn >> 1;
        const float* bias = (p == 0) ? bq : (p == 1) ? bk : bv;
#pragma unroll
        for (int nf = 0; nf < 4; ++nf) {
            int col = nloc0 + wn * 64 + nf * 16 + r;
            float bi = bias[col];
#pragma unroll
            for (int mf = 0; mf < 8; ++mf) {
                int grow0 = browbase + mf * 16 + 4 * g;
                if (p == 0) {
                    for (int reg = 0; reg < 4; ++reg)
                        oq[(size_t)(grow0 + reg) * 512 + col] =
                            (_Float16)(acc[mf][nf][reg] + bi);
                } else if (p == 1) {
                    for (int reg = 0; reg < 4; ++reg)
                        ok[(size_t)(grow0 + reg) * 512 + col] =
                            (_Float16)(acc[mf][nf][reg] + bi);
                } else {
                    int b = grow0 >> 11, s0 = grow0 & 2047;
                    h4 pv;
                    pv[0] = (_Float16)(acc[mf][nf][0] + bi);
                    pv[1] = (_Float16)(acc[mf][nf][1] + bi);
                    pv[2] = (_Float16)(acc[mf][nf][2] + bi);
                    pv[3] = (_Float16)(acc[mf][nf][3] + bi);
                    *(h4*)(&ovt[(size_t)b * (512 * 2048) + (size_t)col * 2048 + s0]) = pv;
                }
            }
        }
    } else {
        float* sb = osc + (size_t)brel * SEQ * (size_t)SEQ;
#pragma unroll
        for (int nf = 0; nf < 4; ++nf) {
            int col = bn * 256 + wn * 64 + nf * 16 + r;
#pragma unroll
            for (int mf = 0; mf < 8; ++mf) {
                int grow0 = browbase + mf * 16 + 4 * g;
                for (int reg = 0; reg < 4; ++reg)
                    sb[(size_t)(grow0 + reg) * SEQ + col] = acc[mf][nf][reg];
            }
        }
    }
}

// ---------------- K0a: split W -> f16 hi/lo, transposed to [n][k] ----------
__global__ __launch_bounds__(256) void k0a_splitw(
    const float* __restrict__ Wq, const float* __restrict__ Wk, const float* __restrict__ Wv,
    _Float16* __restrict__ wh, _Float16* __restrict__ wl) {
    int idx = blockIdx.x * 256 + threadIdx.x;   // [0, 3*512*512)
    int p = idx >> 18;
    int rem = idx & 262143;
    int k = rem >> 9, n = rem & 511;
    const float* W = (p == 0) ? Wq : (p == 1) ? Wk : Wv;
    float w = W[rem];
    _Float16 h = (_Float16)w;
    wh[(p << 18) + (n << 9) + k] = h;
    wl[(p << 18) + (n << 9) + k] = (_Float16)(w - (float)h);
}

// ---------------- K0b: x -> f16 ---------------------------------------------
__global__ __launch_bounds__(256) void k0b_splitx(
    const float* __restrict__ x, _Float16* __restrict__ xh) {
    size_t i = (size_t)(blockIdx.x * 256 + threadIdx.x) * 4;
    float4 v = *(const float4*)(x + i);
    h4 h;
    h[0] = (_Float16)v.x; h[1] = (_Float16)v.y;
    h[2] = (_Float16)v.z; h[3] = (_Float16)v.w;
    *(h4*)(xh + i) = h;
}

// ---------------- K3: row softmax, in-place P(f16) over S(f32) --------------
__global__ __launch_bounds__(256) void k3_softmax(float* __restrict__ sbuf) {
    size_t row = blockIdx.x;
    float* srow = sbuf + row * SEQ;
    int tid = threadIdx.x, lane = tid & 63, wid = tid >> 6;
    float4 v0 = *(const float4*)(srow + tid * 8);
    float4 v1 = *(const float4*)(srow + tid * 8 + 4);
    float m = fmaxf(fmaxf(fmaxf(v0.x, v0.y), fmaxf(v0.z, v0.w)),
                    fmaxf(fmaxf(v1.x, v1.y), fmaxf(v1.z, v1.w)));
    for (int d = 1; d < 64; d <<= 1) m = fmaxf(m, __shfl_xor(m, d));
    __shared__ float red1[4], red2[4];
    if (lane == 0) red1[wid] = m;
    __syncthreads();
    m = fmaxf(fmaxf(red1[0], red1[1]), fmaxf(red1[2], red1[3]));
    float e[8];
    e[0] = __expf(v0.x - m); e[1] = __expf(v0.y - m);
    e[2] = __expf(v0.z - m); e[3] = __expf(v0.w - m);
    e[4] = __expf(v1.x - m); e[5] = __expf(v1.y - m);
    e[6] = __expf(v1.z - m); e[7] = __expf(v1.w - m);
    float s = ((e[0] + e[1]) + (e[2] + e[3])) + ((e[4] + e[5]) + (e[6] + e[7]));
    for (int d = 1; d < 64; d <<= 1) s += __shfl_xor(s, d);
    if (lane == 0) red2[wid] = s;
    __syncthreads();
    s = (red2[0] + red2[1]) + (red2[2] + red2[3]);
    float inv = 1.0f / s;
    h8 ph;
    for (int j = 0; j < 8; ++j) ph[j] = (_Float16)(e[j] * inv);
    *(h8*)((char*)srow + (size_t)tid * 16) = ph;   // P row: first 4KB of S row
}

// ---------------- K4: out = P * V (2-phase 128^2, unchanged) ----------------
__device__ __forceinline__ void stage_g2l(const _Float16* __restrict__ gbase, int pitch_h,
                                          _Float16* lds, int wid, int lane) {
#pragma unroll
    for (int j = 0; j < 2; ++j) {
        int c = (j * 4 + wid) * 64 + lane;
        int row = c >> 2, s = c & 3;
        int col16 = s ^ ((row >> 1) & 3);
        const char* g = (const char*)gbase + (size_t)row * (pitch_h * 2) + col16 * 16;
        char* l = (char*)lds + (j * 4 + wid) * 1024;
        GLOAD_LDS16(g, l);
    }
}
__device__ __forceinline__ h8 fragswz(const _Float16* lds, int row, int g) {
    int g2 = g ^ ((row >> 1) & 3);
    return *(const h8*)((const char*)lds + row * 64 + g2 * 16);
}

__global__ __launch_bounds__(256) void k4_pv(
    const _Float16* __restrict__ pbuf,   // chunk base, row pitch 4096 f16
    const _Float16* __restrict__ vt, float* __restrict__ out, int bat0) {
    __shared__ _Float16 at[2][128 * 32], bt[2][128 * 32];
    int tid = threadIdx.x;
    int m0 = blockIdx.x * 128, n0 = blockIdx.y * 128, bz = blockIdx.z;
    int b = bat0 + bz;
    const _Float16* ab = pbuf + (size_t)bz * (SEQ * 4096) + (size_t)m0 * 4096;
    const _Float16* bb = vt + (size_t)b * (512 * SEQ) + (size_t)n0 * SEQ;
    int wid = tid >> 6, lane = tid & 63, r = lane & 15, g = lane >> 4;
    int mw = wid >> 1, nw = wid & 1;

    f32x4 acc[4][4];
    for (int m = 0; m < 4; ++m)
        for (int n = 0; n < 4; ++n) acc[m][n] = (f32x4)(0.0f);

    stage_g2l(ab, 4096, at[0], wid, lane);
    stage_g2l(bb, SEQ, bt[0], wid, lane);
    __syncthreads();

    int cur = 0;
    for (int kt = 0; kt < 64; ++kt) {
        if (kt + 1 < 64) {
            int k1 = (kt + 1) * 32;
            stage_g2l(ab + k1, 4096, at[cur ^ 1], wid, lane);
            stage_g2l(bb + k1, SEQ, bt[cur ^ 1], wid, lane);
        }
        h8 af[4], bf[4];
#pragma unroll
        for (int m = 0; m < 4; ++m) af[m] = fragswz(at[cur], mw * 64 + m * 16 + r, g);
#pragma unroll
        for (int n = 0; n < 4; ++n) bf[n] = fragswz(bt[cur], nw * 64 + n * 16 + r, g);
#pragma unroll
        for (int m = 0; m < 4; ++m)
#pragma unroll
            for (int n = 0; n < 4; ++n)
                acc[m][n] = MFMA16(af[m], bf[n], acc[m][n]);
        __syncthreads();
        cur ^= 1;
    }

    for (int n = 0; n < 4; ++n) {
        int col = n0 + nw * 64 + n * 16 + r;
        for (int m = 0; m < 4; ++m) {
            int grow0 = m0 + mw * 64 + m * 16 + 4 * g;
            for (int reg = 0; reg < 4; ++reg)
                out[(size_t)(b * SEQ + grow0 + reg) * 512 + col] = acc[m][n][reg];
        }
    }
}

// ---------------------------------------------------------------------------
extern "C" void kernel_launch(void* const* d_in, const int* in_sizes, int n_in,
                              void* d_out, int out_size, void* d_ws, size_t ws_size,
                              hipStream_t stream) {
    const float* x  = (const float*)d_in[0];
    const float* Wq = (const float*)d_in[1];
    const float* bq = (const float*)d_in[2];
    const float* Wk = (const float*)d_in[3];
    const float* bk = (const float*)d_in[4];
    const float* Wv = (const float*)d_in[5];
    const float* bv = (const float*)d_in[6];
    float* out = (float*)d_out;

    char* ws = (char*)d_ws;
    const size_t QSZ = 16777216;   // 16384*512*2B (also = one batch of S fp32)
    _Float16* wh = (_Float16*)(ws);
    _Float16* wl = (_Float16*)(ws + 1572864);
    _Float16* xh = (_Float16*)(ws + 3145728);
    _Float16* qh = (_Float16*)(ws + 3145728 + 1 * QSZ);
    _Float16* kh = (_Float16*)(ws + 3145728 + 2 * QSZ);
    _Float16* vt = (_Float16*)(ws + 3145728 + 3 * QSZ);
    const size_t sbase = 3145728 + 4 * QSZ;          // 70,254,592

    hipFuncSetAttribute((const void*)gemm256<0>,
                        hipFuncAttributeMaxDynamicSharedMemorySize, 131072);
    hipFuncSetAttribute((const void*)gemm256<1>,
                        hipFuncAttributeMaxDynamicSharedMemorySize, 131072);

    k0a_splitw<<<3072, 256, 0, stream>>>(Wq, Wk, Wv, wh, wl);
    k0b_splitx<<<8192, 256, 0, stream>>>(x, xh);
    gemm256<0><<<384, 512, 131072, stream>>>(xh, wh, wl, bq, bk, bv,
                                             qh, kh, vt, nullptr, 0);

    size_t avail = (ws_size > sbase) ? (ws_size - sbase) : 0;
    int chunk = (int)(avail / QSZ);
    if (chunk < 1) chunk = 1;
    if (chunk > 8) chunk = 8;
    float* sc = (float*)(ws + sbase);
    for (int b0 = 0; b0 < 8; b0 += chunk) {
        int nb = (8 - b0 < chunk) ? (8 - b0) : chunk;
        gemm256<1><<<nb * 64, 512, 131072, stream>>>(qh, kh, nullptr,
                                                     nullptr, nullptr, nullptr,
                                                     nullptr, nullptr, nullptr, sc, b0);
        k3_softmax<<<dim3(nb * SEQ), 256, 0, stream>>>(sc);
        k4_pv<<<dim3(16, 4, nb), 256, 0, stream>>>((const _Float16*)sc, vt, out, b0);
    }
}